// Round 1
// baseline (1478.359 us; speedup 1.0000x reference)
//
#include <hip/hip_runtime.h>
#include <hip/hip_bf16.h>

// Problem constants (fixed by reference): T=2048, K=8, E=64, H=2048, I=768
#define TOPK   8
#define NEXP   64
#define HID    2048
#define INTER  768
#define CAP    256   // pairs per expert = T*K/E (balanced routing guaranteed)

typedef float  f32x4  __attribute__((ext_vector_type(4)));
typedef __bf16 bf16x8 __attribute__((ext_vector_type(8)));
typedef unsigned short u16x8 __attribute__((ext_vector_type(8)));

// fp32 -> bf16 round-to-nearest-even (raw bits; inputs are normal floats)
__device__ __forceinline__ unsigned short f2bf(float f) {
  unsigned int u = __float_as_uint(f);
  u += 0x7fffu + ((u >> 16) & 1u);
  return (unsigned short)(u >> 16);
}

// ---------------------------------------------------------------------------
// Kernel 1: routing + gather. One wave per (token, slot) pair.
// Builds Xg[e*CAP + pos][H] (bf16), tok_arr/w_arr per slot.
// Intra-expert slot order comes from atomicAdd (nondeterministic) — the final
// scatter-add is invariant to it.
// ---------------------------------------------------------------------------
__global__ __launch_bounds__(512) void route_gather(
    const float* __restrict__ hs, const int* __restrict__ tki,
    const float* __restrict__ tkw, unsigned short* __restrict__ Xg,
    int* __restrict__ tok_arr, float* __restrict__ w_arr,
    int* __restrict__ cnt) {
  int lane = threadIdx.x & 63;
  int p = blockIdx.x * 8 + (threadIdx.x >> 6);   // pair index, 16384 waves total
  int slot = 0;
  if (lane == 0) {
    int e = tki[p];
    int pos = atomicAdd(&cnt[e], 1);
    slot = e * CAP + pos;
    tok_arr[slot] = p >> 3;      // p / TOPK
    w_arr[slot] = tkw[p];
  }
  slot = __shfl(slot, 0);
  const float* src = hs + (size_t)(p >> 3) * HID;
  unsigned short* dst = Xg + (size_t)slot * HID;
#pragma unroll
  for (int i = 0; i < 4; ++i) {
    int base = i * 512 + lane * 8;
    float4 f0 = *(const float4*)(src + base);
    float4 f1 = *(const float4*)(src + base + 4);
    u16x8 pk;
    pk[0] = f2bf(f0.x); pk[1] = f2bf(f0.y); pk[2] = f2bf(f0.z); pk[3] = f2bf(f0.w);
    pk[4] = f2bf(f1.x); pk[5] = f2bf(f1.y); pk[6] = f2bf(f1.z); pk[7] = f2bf(f1.w);
    *(u16x8*)(dst + base) = pk;
  }
}

// ---------------------------------------------------------------------------
// Kernel 2: gate_up GEMM + fused SwiGLU.
// Block = 512 thr (8 waves). Per block: expert e, N-tile nt (64 cols of I).
// Computes gate[256x64] (waves w&1==0) and up[256x64] (waves w&1==1) so every
// weight element is read exactly once (BM = 256 = full expert capacity).
// LDS: As[256][64] bf16 (32KB) + Bs[128][64] bf16 (16KB), XOR-swizzled in
// 16B granules: granule' = granule ^ (row&7)  -> conflict-free ds_read_b128.
// Epilogue: up-waves dump acc to LDS, gate-waves compute silu(g)*u -> Hbuf.
// ---------------------------------------------------------------------------
__global__ __launch_bounds__(512) void g1_swiglu(
    const unsigned short* __restrict__ Xg, const float* __restrict__ gup,
    unsigned short* __restrict__ Hbuf) {
  __shared__ __align__(16) unsigned char smem[65536];
  int b = blockIdx.x;
  b = (b & 7) * (gridDim.x >> 3) + (b >> 3);     // XCD swizzle (768 % 8 == 0)
  int e = b / 12, nt = b % 12;
  int tid = threadIdx.x, lane = tid & 63, w = tid >> 6;
  int half = w & 1, mrow = w >> 1;               // half: 0=gate 1=up; rows mrow*64..
  const unsigned short* Ae = Xg + (size_t)e * CAP * HID;
  const float* Be = gup + (size_t)e * (2 * INTER) * HID;

  f32x4 acc[4][4];
  const f32x4 z = {0.f, 0.f, 0.f, 0.f};
#pragma unroll
  for (int i = 0; i < 4; ++i)
#pragma unroll
    for (int j = 0; j < 4; ++j) acc[i][j] = z;

  for (int kt = 0; kt < HID / 64; ++kt) {
    int k0 = kt * 64;
    // stage A: 256x64 bf16 = 2048 granules of 16B, 4 per thread
#pragma unroll
    for (int i = 0; i < 4; ++i) {
      int g = tid + i * 512;
      int row = g >> 3, gr = g & 7;
      uint4 v = *(const uint4*)(Ae + (size_t)row * HID + k0 + gr * 8);
      *(uint4*)(smem + row * 128 + ((gr ^ (row & 7)) << 4)) = v;
    }
    // stage B: 128 rows (64 gate + 64 up) x 64 fp32 -> bf16; 2 chunks/thread
#pragma unroll
    for (int i = 0; i < 2; ++i) {
      int c = tid + i * 512;
      int row = c >> 3, gr = c & 7;
      int brow = (row < 64) ? (nt * 64 + row) : (INTER + nt * 64 + row - 64);
      const float* s = Be + (size_t)brow * HID + k0 + gr * 8;
      float4 f0 = *(const float4*)s;
      float4 f1 = *(const float4*)(s + 4);
      u16x8 pk;
      pk[0] = f2bf(f0.x); pk[1] = f2bf(f0.y); pk[2] = f2bf(f0.z); pk[3] = f2bf(f0.w);
      pk[4] = f2bf(f1.x); pk[5] = f2bf(f1.y); pk[6] = f2bf(f1.z); pk[7] = f2bf(f1.w);
      *(u16x8*)(smem + 32768 + row * 128 + ((gr ^ (row & 7)) << 4)) = pk;
    }
    __syncthreads();
    // compute: 2 k-slices of 32, 4x4 fragments of 16x16 per wave
#pragma unroll
    for (int kk = 0; kk < 2; ++kk) {
      bf16x8 av[4], bv[4];
#pragma unroll
      for (int fm = 0; fm < 4; ++fm) {
        int row = mrow * 64 + fm * 16 + (lane & 15);
        int gr = (kk * 4 + (lane >> 4)) ^ (row & 7);
        av[fm] = *(const bf16x8*)(smem + row * 128 + (gr << 4));
      }
#pragma unroll
      for (int fn = 0; fn < 4; ++fn) {
        int row = half * 64 + fn * 16 + (lane & 15);
        int gr = (kk * 4 + (lane >> 4)) ^ (row & 7);
        bv[fn] = *(const bf16x8*)(smem + 32768 + row * 128 + (gr << 4));
      }
#pragma unroll
      for (int fm = 0; fm < 4; ++fm)
#pragma unroll
        for (int fn = 0; fn < 4; ++fn)
          acc[fm][fn] = __builtin_amdgcn_mfma_f32_16x16x32_bf16(
              av[fm], bv[fn], acc[fm][fn], 0, 0, 0);
    }
    __syncthreads();
  }

  // epilogue: SwiGLU via LDS exchange (reuses staging LDS; all reads done)
  float* Ex = (float*)smem;   // [256][64] fp32 = 64KB
  if (half == 1) {
#pragma unroll
    for (int fm = 0; fm < 4; ++fm)
#pragma unroll
      for (int fn = 0; fn < 4; ++fn)
#pragma unroll
        for (int j = 0; j < 4; ++j) {
          int r = mrow * 64 + fm * 16 + ((lane >> 4) << 2) + j;  // C/D: row=(lane>>4)*4+reg
          int cl = fn * 16 + (lane & 15);                        //      col=lane&15
          Ex[r * 64 + cl] = acc[fm][fn][j];
        }
  }
  __syncthreads();
  if (half == 0) {
#pragma unroll
    for (int fm = 0; fm < 4; ++fm)
#pragma unroll
      for (int fn = 0; fn < 4; ++fn)
#pragma unroll
        for (int j = 0; j < 4; ++j) {
          int r = mrow * 64 + fm * 16 + ((lane >> 4) << 2) + j;
          int cl = fn * 16 + (lane & 15);
          float g = acc[fm][fn][j];
          float u = Ex[r * 64 + cl];
          float hv = g / (1.0f + __expf(-g)) * u;   // silu(g)*u
          Hbuf[((size_t)e * CAP + r) * INTER + nt * 64 + cl] = f2bf(hv);
        }
  }
}

// ---------------------------------------------------------------------------
// Kernel 3: down GEMM + weighted scatter-add.
// Block: expert e, 64-col tile of H. A = h[256][768] bf16 (ws), B = down rows
// (output cols) fp32 -> bf16. Epilogue: acc * w[slot] atomicAdd into out.
// ---------------------------------------------------------------------------
__global__ __launch_bounds__(512) void g2_down(
    const unsigned short* __restrict__ Hbuf, const float* __restrict__ dwn,
    const int* __restrict__ tok_arr, const float* __restrict__ w_arr,
    float* __restrict__ out) {
  __shared__ __align__(16) unsigned char smem[40960];
  int b = blockIdx.x;
  b = (b & 7) * (gridDim.x >> 3) + (b >> 3);     // XCD swizzle (2048 % 8 == 0)
  int e = b >> 5, nt = b & 31;
  int tid = threadIdx.x, lane = tid & 63, w = tid >> 6;
  int wn = w & 1, wm = w >> 1;                   // wave tile: rows wm*64, cols wn*32
  const unsigned short* Ae = Hbuf + (size_t)e * CAP * INTER;
  const float* Be = dwn + ((size_t)e * HID + nt * 64) * INTER;

  f32x4 acc[4][2];
  const f32x4 z = {0.f, 0.f, 0.f, 0.f};
#pragma unroll
  for (int i = 0; i < 4; ++i) { acc[i][0] = z; acc[i][1] = z; }

  for (int kt = 0; kt < INTER / 64; ++kt) {
    int k0 = kt * 64;
    // stage A: 256x64 bf16, 4 granules/thread
#pragma unroll
    for (int i = 0; i < 4; ++i) {
      int g = tid + i * 512;
      int row = g >> 3, gr = g & 7;
      uint4 v = *(const uint4*)(Ae + (size_t)row * INTER + k0 + gr * 8);
      *(uint4*)(smem + row * 128 + ((gr ^ (row & 7)) << 4)) = v;
    }
    // stage B: 64x64 fp32 -> bf16, 1 chunk/thread
    {
      int row = tid >> 3, gr = tid & 7;
      const float* s = Be + (size_t)row * INTER + k0 + gr * 8;
      float4 f0 = *(const float4*)s;
      float4 f1 = *(const float4*)(s + 4);
      u16x8 pk;
      pk[0] = f2bf(f0.x); pk[1] = f2bf(f0.y); pk[2] = f2bf(f0.z); pk[3] = f2bf(f0.w);
      pk[4] = f2bf(f1.x); pk[5] = f2bf(f1.y); pk[6] = f2bf(f1.z); pk[7] = f2bf(f1.w);
      *(u16x8*)(smem + 32768 + row * 128 + ((gr ^ (row & 7)) << 4)) = pk;
    }
    __syncthreads();
#pragma unroll
    for (int kk = 0; kk < 2; ++kk) {
      bf16x8 av[4], bv[2];
#pragma unroll
      for (int fm = 0; fm < 4; ++fm) {
        int row = wm * 64 + fm * 16 + (lane & 15);
        int gr = (kk * 4 + (lane >> 4)) ^ (row & 7);
        av[fm] = *(const bf16x8*)(smem + row * 128 + (gr << 4));
      }
#pragma unroll
      for (int fn = 0; fn < 2; ++fn) {
        int row = wn * 32 + fn * 16 + (lane & 15);
        int gr = (kk * 4 + (lane >> 4)) ^ (row & 7);
        bv[fn] = *(const bf16x8*)(smem + 32768 + row * 128 + (gr << 4));
      }
#pragma unroll
      for (int fm = 0; fm < 4; ++fm)
#pragma unroll
        for (int fn = 0; fn < 2; ++fn)
          acc[fm][fn] = __builtin_amdgcn_mfma_f32_16x16x32_bf16(
              av[fm], bv[fn], acc[fm][fn], 0, 0, 0);
    }
    __syncthreads();
  }

  // epilogue: scale by routing weight, scatter-add into out[token][col]
#pragma unroll
  for (int fm = 0; fm < 4; ++fm) {
#pragma unroll
    for (int j = 0; j < 4; ++j) {
      int r = wm * 64 + fm * 16 + ((lane >> 4) << 2) + j;
      int slot = e * CAP + r;
      int tok = tok_arr[slot];
      float wgt = w_arr[slot];
#pragma unroll
      for (int fn = 0; fn < 2; ++fn) {
        int col = nt * 64 + wn * 32 + fn * 16 + (lane & 15);
        atomicAdd(&out[(size_t)tok * HID + col], acc[fm][fn][j] * wgt);
      }
    }
  }
}

// ---------------------------------------------------------------------------
// ws layout (total ~92.4 MB):
//   [0,            67108864)  Xg    : gathered tokens bf16 [E*CAP][HID]
//   [67108864,     92274688)  Hbuf  : swiglu output bf16  [E*CAP][INTER]
//   [92274688,     92340224)  tok_arr[E*CAP] int32
//   [92340224,     92405760)  w_arr  [E*CAP] fp32
//   [92405760,     92406016)  cnt    [NEXP]  int32
// ---------------------------------------------------------------------------
extern "C" void kernel_launch(void* const* d_in, const int* in_sizes, int n_in,
                              void* d_out, int out_size, void* d_ws, size_t ws_size,
                              hipStream_t stream) {
  const float* hs  = (const float*)d_in[0];
  const int*   tki = (const int*)d_in[1];
  const float* tkw = (const float*)d_in[2];
  const float* gup = (const float*)d_in[3];
  const float* dwn = (const float*)d_in[4];
  float* out = (float*)d_out;

  char* ws = (char*)d_ws;
  unsigned short* Xg   = (unsigned short*)ws;
  unsigned short* Hbuf = (unsigned short*)(ws + 67108864);
  int*   tok_arr = (int*)(ws + 92274688);
  float* w_arr   = (float*)(ws + 92340224);
  int*   cnt     = (int*)(ws + 92405760);

  hipMemsetAsync(cnt, 0, 256, stream);
  hipMemsetAsync(d_out, 0, (size_t)out_size * sizeof(float), stream);

  route_gather<<<2048, 512, 0, stream>>>(hs, tki, tkw, Xg, tok_arr, w_arr, cnt);
  g1_swiglu<<<768, 512, 0, stream>>>(Xg, gup, Hbuf);
  g2_down<<<2048, 512, 0, stream>>>(Hbuf, dwn, tok_arr, w_arr, out);
}